// Round 8
// baseline (454.530 us; speedup 1.0000x reference)
//
#include <hip/hip_runtime.h>
#include <cstdint>
#include <cstddef>

constexpr int Bc = 2, Lc = 2048, DM = 1024, DI = 2048, DS = 16, DR = 64, NX = 96;
constexpr int BL = Bc * Lc;          // 4096
constexpr int NC = 32, CH = 64;      // scan chunks / chunk length
constexpr int BDS = Bc * DI * DS;    // 65536
constexpr int NSK = 8;               // x_proj split-K factor
constexpr float LOG2E = 1.44269504f;

typedef __attribute__((ext_vector_type(8))) short bf16x8;
typedef __attribute__((ext_vector_type(4))) float f32x4;
typedef unsigned short u16;

__device__ __forceinline__ u16 f2b(float f) {          // fp32 -> bf16 (RNE)
  uint32_t u = __float_as_uint(f);
  return (u16)((u + 0x7FFFu + ((u >> 16) & 1u)) >> 16);
}
__device__ __forceinline__ float b2f(u16 h) {
  return __uint_as_float(((uint32_t)h) << 16);
}

// ---------------------------------------------------------------------------
// Fused conversion: all fp32 inputs -> bf16 hi/lo planes in ONE kernel.
// Segments: x | W_in | W_xproj(pad 96->128 rows) | W_dtproj | W_out.
// ---------------------------------------------------------------------------
constexpr int S0 = BL * DM / 4;          // x        1,048,576 float4
constexpr int S1 = 2 * DI * DM / 4;      // W_in     1,048,576
constexpr int S2 = 128 * DI / 4;         // W_xproj     65,536 (padded dest)
constexpr int S3 = DI * DR / 4;          // W_dtproj    32,768
constexpr int S4 = DM * DI / 4;          // W_out      524,288
constexpr int CVT_TOT = S0 + S1 + S2 + S3 + S4;   // 2,719,744

__global__ __launch_bounds__(256) void cvt_all(
    const float* __restrict__ x, const float* __restrict__ W_in,
    const float* __restrict__ W_xproj, const float* __restrict__ W_dtproj,
    const float* __restrict__ W_out,
    u16* __restrict__ xh, u16* __restrict__ xl,
    u16* __restrict__ Wih, u16* __restrict__ Wil,
    u16* __restrict__ Wxh, u16* __restrict__ Wxl,
    u16* __restrict__ Wdh, u16* __restrict__ Wdl,
    u16* __restrict__ Woh, u16* __restrict__ Wol) {
  int i = blockIdx.x * 256 + threadIdx.x;
  if (i >= CVT_TOT) return;
  const float* src; u16 *dh, *dl; int idx; bool zero = false;
  if (i < S0)                { src = x;        dh = xh;  dl = xl;  idx = i; }
  else if (i < S0+S1)        { src = W_in;     dh = Wih; dl = Wil; idx = i - S0; }
  else if (i < S0+S1+S2)     { src = W_xproj;  dh = Wxh; dl = Wxl; idx = i - S0 - S1;
                               if (((idx * 4) >> 11) >= 96) zero = true; }
  else if (i < S0+S1+S2+S3)  { src = W_dtproj; dh = Wdh; dl = Wdl; idx = i - S0 - S1 - S2; }
  else                       { src = W_out;    dh = Woh; dl = Wol; idx = i - S0 - S1 - S2 - S3; }
  float4 v = zero ? make_float4(0.f, 0.f, 0.f, 0.f)
                  : reinterpret_cast<const float4*>(src)[idx];
  ushort4 H, L;
  H.x = f2b(v.x); L.x = f2b(v.x - b2f(H.x));
  H.y = f2b(v.y); L.y = f2b(v.y - b2f(H.y));
  H.z = f2b(v.z); L.z = f2b(v.z - b2f(H.z));
  H.w = f2b(v.w); L.w = f2b(v.w - b2f(H.w));
  reinterpret_cast<ushort4*>(dh)[idx] = H;
  reinterpret_cast<ushort4*>(dl)[idx] = L;
}

// ---------------------------------------------------------------------------
// Split-bf16 MFMA GEMM: C[M,N](fp32) = A[M,K] @ B[N,K]^T via hi/lo planes.
// r6 geometry (proven best): 128x128 tile, BK=32, 4 waves (2x2), 64 KB
// double-buffered LDS (2 blocks/CU). NEW: T4 counted-vmcnt 2-deep pipeline —
// prologue stages tiles 0,1; per iter: s_waitcnt vmcnt(8) (oldest 8 = this
// tile) -> s_barrier -> ds_read + 48 MFMA -> s_barrier -> stage tile t+2
// into the buffer just consumed. No vmcnt(0) drain in the main loop.
// ---------------------------------------------------------------------------
__device__ __forceinline__ void stage_tile(
    const u16* __restrict__ g, u16* lds, int row0, int ld, int k0,
    int w, int lane) {
  #pragma unroll
  for (int i = 0; i < 2; ++i) {
    const int base = w * 1024 + i * 4096;          // wave-uniform byte base
    const int o = base + lane * 16;                // this lane's byte slot
    const int row = o >> 6;                        // 64B per row (32 bf16)
    const int sl = ((o >> 4) & 3) ^ ((row >> 1) & 3);  // inverse swizzle
    const u16* src = g + (size_t)(row0 + row) * ld + (k0 + sl * 8);
    __builtin_amdgcn_global_load_lds(
        (const __attribute__((address_space(1))) unsigned int*)src,
        (__attribute__((address_space(3))) unsigned int*)(lds + base / 2),
        16, 0, 0);
  }
}

__device__ __forceinline__ void stage4(
    const u16* __restrict__ Ah, const u16* __restrict__ Al,
    const u16* __restrict__ Bh, const u16* __restrict__ Bl,
    u16* buf /* [4][4096] */, int bm, int bn, int lda, int ldb,
    int k0, int w, int lane) {
  stage_tile(Ah, buf + 0 * 4096, bm, lda, k0, w, lane);
  stage_tile(Al, buf + 1 * 4096, bm, lda, k0, w, lane);
  stage_tile(Bh, buf + 2 * 4096, bn, ldb, k0, w, lane);
  stage_tile(Bl, buf + 3 * 4096, bn, ldb, k0, w, lane);
}

__device__ __forceinline__ bf16x8 ld_frag(const u16* plane, int rowbase, int lane) {
  const int row = rowbase + (lane & 15);
  const int kb = (lane >> 4) ^ ((row >> 1) & 3);   // swizzled 16B slot
  return *reinterpret_cast<const bf16x8*>(
      reinterpret_cast<const char*>(plane) + row * 64 + kb * 16);
}

template<int EPI>
__global__ __launch_bounds__(256) void gemm_mfma(
    const u16* __restrict__ Ah, const u16* __restrict__ Al,
    const u16* __restrict__ Bh, const u16* __restrict__ Bl,
    const float* __restrict__ bias, float* __restrict__ C,
    int M, int N, int kEff, int lda, int ldb, int ldc,
    size_t cSplitStride) {
  __shared__ __align__(16) u16 lds[2][4][4096];    // 64 KB, double-buffered
  const int tid = threadIdx.x;
  const int lane = tid & 63, w = tid >> 6;
  const int wr = w >> 1, wc = w & 1;
  const int bm = blockIdx.x * 128, bn = blockIdx.y * 128;
  const int sk = blockIdx.z;
  Ah += (size_t)sk * kEff; Al += (size_t)sk * kEff;
  Bh += (size_t)sk * kEff; Bl += (size_t)sk * kEff;
  C  += (size_t)sk * cSplitStride;

  f32x4 acc[4][4] = {};
  const int nt = kEff >> 5;                        // BK=32, nt >= 2 always

  // prologue: stage tiles 0 and 1 (16 outstanding loads/thread)
  stage4(Ah, Al, Bh, Bl, &lds[0][0][0], bm, bn, lda, ldb, 0, w, lane);
  stage4(Ah, Al, Bh, Bl, &lds[1][0][0], bm, bn, lda, ldb, 32, w, lane);

  int cur = 0;
  for (int t = 0; t < nt; ++t) {
    // wait the OLDEST 8 loads (tile t); tile t+1's stay in flight
    if (t + 1 < nt) asm volatile("s_waitcnt vmcnt(8)" ::: "memory");
    else            asm volatile("s_waitcnt vmcnt(0)" ::: "memory");
    __builtin_amdgcn_s_barrier();                  // all waves' tile-t landed

    const u16* Lb = &lds[cur][0][0];
    bf16x8 ah[4], al[4], bh[4], bl[4];
    #pragma unroll
    for (int m = 0; m < 4; ++m) {
      ah[m] = ld_frag(Lb + 0 * 4096, wr * 64 + m * 16, lane);
      al[m] = ld_frag(Lb + 1 * 4096, wr * 64 + m * 16, lane);
    }
    #pragma unroll
    for (int n = 0; n < 4; ++n) {
      bh[n] = ld_frag(Lb + 2 * 4096, wc * 64 + n * 16, lane);
      bl[n] = ld_frag(Lb + 3 * 4096, wc * 64 + n * 16, lane);
    }
    __builtin_amdgcn_s_setprio(1);
    #pragma unroll
    for (int m = 0; m < 4; ++m)
      #pragma unroll
      for (int n = 0; n < 4; ++n)
        acc[m][n] = __builtin_amdgcn_mfma_f32_16x16x32_bf16(ah[m], bh[n], acc[m][n], 0, 0, 0);
    #pragma unroll
    for (int m = 0; m < 4; ++m)
      #pragma unroll
      for (int n = 0; n < 4; ++n)
        acc[m][n] = __builtin_amdgcn_mfma_f32_16x16x32_bf16(ah[m], bl[n], acc[m][n], 0, 0, 0);
    #pragma unroll
    for (int m = 0; m < 4; ++m)
      #pragma unroll
      for (int n = 0; n < 4; ++n)
        acc[m][n] = __builtin_amdgcn_mfma_f32_16x16x32_bf16(al[m], bh[n], acc[m][n], 0, 0, 0);
    __builtin_amdgcn_s_setprio(0);
    __builtin_amdgcn_s_barrier();                  // all waves done reading lds[cur]
    if (t + 2 < nt)                                // overwrite it with tile t+2
      stage4(Ah, Al, Bh, Bl, &lds[cur][0][0], bm, bn, lda, ldb,
             (t + 2) * 32, w, lane);
    cur ^= 1;
  }

  // epilogue: C/D layout col = lane&15, row = (lane>>4)*4 + r
  const int rbase = (lane >> 4) * 4;
  const int cidx = lane & 15;
  #pragma unroll
  for (int m = 0; m < 4; ++m) {
    int grow0 = bm + wr * 64 + m * 16 + rbase;
    #pragma unroll
    for (int n = 0; n < 4; ++n) {
      int gcol = bn + wc * 64 + n * 16 + cidx;
      if (gcol < N) {
        #pragma unroll
        for (int r = 0; r < 4; ++r) {
          float v = acc[m][n][r];
          if (EPI == 1) {
            v += bias[gcol];
            v = fmaxf(v, 0.f) + log1pf(expf(-fabsf(v)));
          }
          C[(size_t)(grow0 + r) * ldc + gcol] = v;
        }
      }
    }
  }
}

// ---------------------------------------------------------------------------
// x_proj split-K reduce: sum NSK partials -> xdbl fp32 + hi/lo planes.
// ---------------------------------------------------------------------------
__global__ __launch_bounds__(256) void xproj_reduce(
    const float* __restrict__ pbuf, float* __restrict__ xdbl,
    u16* __restrict__ xdh, u16* __restrict__ xdl) {
  int i = blockIdx.x * 256 + threadIdx.x;          // over BL*NX/4
  const float4* p = reinterpret_cast<const float4*>(pbuf);
  float4 s = p[i];
  #pragma unroll
  for (int sk = 1; sk < NSK; ++sk) {
    float4 v = p[(size_t)sk * (BL * NX / 4) + i];
    s.x += v.x; s.y += v.y; s.z += v.z; s.w += v.w;
  }
  reinterpret_cast<float4*>(xdbl)[i] = s;
  ushort4 H, L;
  H.x = f2b(s.x); L.x = f2b(s.x - b2f(H.x));
  H.y = f2b(s.y); L.y = f2b(s.y - b2f(H.y));
  H.z = f2b(s.z); L.z = f2b(s.z - b2f(H.z));
  H.w = f2b(s.w); L.w = f2b(s.w - b2f(H.w));
  reinterpret_cast<ushort4*>(xdh)[i] = H;
  reinterpret_cast<ushort4*>(xdl)[i] = L;
}

// ---------------------------------------------------------------------------
// Depthwise causal conv (D_CONV=4) + bias + SiLU, 4 elements/thread.
// ---------------------------------------------------------------------------
__global__ __launch_bounds__(256) void conv_silu4(
    const float* __restrict__ xz, const float* __restrict__ w,
    const float* __restrict__ bias, u16* __restrict__ uch,
    u16* __restrict__ ucl) {
  int i = blockIdx.x * 256 + threadIdx.x;          // over BL*DI/4
  int d4 = (i << 2) & (DI - 1);
  int bl = i >> 9;                                 // (i*4)/DI
  int b  = bl >> 11;
  int l  = bl & (Lc - 1);
  const float4* wrow = reinterpret_cast<const float4*>(&w[d4 * 4]);
  float4 w0 = wrow[0], w1 = wrow[1], w2 = wrow[2], w3 = wrow[3];
  float4 a = *reinterpret_cast<const float4*>(&bias[d4]);
  #pragma unroll
  for (int k = 0; k < 4; ++k) {
    int ls = l - 3 + k;
    if (ls >= 0) {
      float4 xv = *reinterpret_cast<const float4*>(
          &xz[((size_t)(b * Lc + ls)) * (2 * DI) + d4]);
      a.x = fmaf(xv.x, (&w0.x)[k], a.x);
      a.y = fmaf(xv.y, (&w1.x)[k], a.y);
      a.z = fmaf(xv.z, (&w2.x)[k], a.z);
      a.w = fmaf(xv.w, (&w3.x)[k], a.w);
    }
  }
  a.x = a.x * __frcp_rn(1.f + __expf(-a.x));
  a.y = a.y * __frcp_rn(1.f + __expf(-a.y));
  a.z = a.z * __frcp_rn(1.f + __expf(-a.z));
  a.w = a.w * __frcp_rn(1.f + __expf(-a.w));
  ushort4 H, L;
  H.x = f2b(a.x); L.x = f2b(a.x - b2f(H.x));
  H.y = f2b(a.y); L.y = f2b(a.y - b2f(H.y));
  H.z = f2b(a.z); L.z = f2b(a.z - b2f(H.z));
  H.w = f2b(a.w); L.w = f2b(a.w - b2f(H.w));
  reinterpret_cast<ushort4*>(uch)[i] = H;
  reinterpret_cast<ushort4*>(ucl)[i] = L;
}

// ---------------------------------------------------------------------------
// Chunked scan, pass A (d-parallel): one thread per (b, d, chunk); 16 states
// in registers. Stores P[s] = exp2(Av2[s]*sum(dt)) and local final h[s].
// ---------------------------------------------------------------------------
__global__ __launch_bounds__(256) void scan_chunk_local(
    const float* __restrict__ delta, const u16* __restrict__ uch,
    const u16* __restrict__ ucl, const float* __restrict__ xdbl,
    const float* __restrict__ A_log, float* __restrict__ Pa,
    float* __restrict__ hA) {
  const int t = blockIdx.x * 256 + threadIdx.x;
  const int d = t & (DI - 1);
  const int b = (t >> 11) & (Bc - 1);
  const int c = t >> 12;
  const int bd = (b << 11) | d;

  float Av2[DS];
  {
    const float4* ap = reinterpret_cast<const float4*>(&A_log[(size_t)d * DS]);
    #pragma unroll
    for (int q = 0; q < 4; ++q) {
      float4 a = ap[q];
      Av2[4*q+0] = -LOG2E * __expf(a.x);
      Av2[4*q+1] = -LOG2E * __expf(a.y);
      Av2[4*q+2] = -LOG2E * __expf(a.z);
      Av2[4*q+3] = -LOG2E * __expf(a.w);
    }
  }
  const size_t rowbase = (size_t)(b * Lc + c * CH);
  const float* dp  = delta + rowbase * DI + d;
  const u16*   uhp = uch   + rowbase * DI + d;
  const u16*   ulp = ucl   + rowbase * DI + d;
  const float4* xp = reinterpret_cast<const float4*>(xdbl + rowbase * NX + DR);

  float h[DS] = {};
  float S = 0.f;
  float dt = dp[0];
  float ut = b2f(uhp[0]) + b2f(ulp[0]);
  float4 B0 = xp[0], B1 = xp[1], B2 = xp[2], B3 = xp[3];

  for (int l = 0; l < CH; ++l) {
    const int ln = (l + 1 < CH) ? l + 1 : l;
    float dtn = dp[ln * DI];
    float utn = b2f(uhp[ln * DI]) + b2f(ulp[ln * DI]);
    const float4* xn = xp + ln * (NX / 4);
    float4 B0n = xn[0], B1n = xn[1], B2n = xn[2], B3n = xn[3];

    float Bs[16];
    *reinterpret_cast<float4*>(&Bs[0])  = B0;
    *reinterpret_cast<float4*>(&Bs[4])  = B1;
    *reinterpret_cast<float4*>(&Bs[8])  = B2;
    *reinterpret_cast<float4*>(&Bs[12]) = B3;
    const float dtu = dt * ut;
    S += dt;
    #pragma unroll
    for (int s = 0; s < DS; ++s) {
      float dA = exp2f(dt * Av2[s]);
      h[s] = fmaf(dA, h[s], dtu * Bs[s]);
    }
    dt = dtn; ut = utn; B0 = B0n; B1 = B1n; B2 = B2n; B3 = B3n;
  }

  float4* Pp = reinterpret_cast<float4*>(&Pa[(size_t)c * BDS + (size_t)bd * DS]);
  float4* Hp = reinterpret_cast<float4*>(&hA[(size_t)c * BDS + (size_t)bd * DS]);
  #pragma unroll
  for (int q = 0; q < 4; ++q) {
    float4 pv, hv;
    pv.x = exp2f(Av2[4*q+0] * S); pv.y = exp2f(Av2[4*q+1] * S);
    pv.z = exp2f(Av2[4*q+2] * S); pv.w = exp2f(Av2[4*q+3] * S);
    hv.x = h[4*q+0]; hv.y = h[4*q+1]; hv.z = h[4*q+2]; hv.w = h[4*q+3];
    Pp[q] = pv; Hp[q] = hv;
  }
}

// ---------------------------------------------------------------------------
// Pass B: serial carry across chunks; h0 written in-place over Pa.
// ---------------------------------------------------------------------------
__global__ __launch_bounds__(256) void scan_chunk_carry(
    float* Pa_h0, const float* __restrict__ hA) {
  const int t = blockIdx.x * 256 + threadIdx.x; // over BDS
  float pa[NC], ha[NC];
  #pragma unroll
  for (int c = 0; c < NC; ++c) {
    pa[c] = Pa_h0[(size_t)c * BDS + t];
    ha[c] = hA[(size_t)c * BDS + t];
  }
  float h = 0.f;
  #pragma unroll
  for (int c = 0; c < NC; ++c) {
    Pa_h0[(size_t)c * BDS + t] = h;
    h = fmaf(pa[c], h, ha[c]);
  }
}

// ---------------------------------------------------------------------------
// Pass C (d-parallel): re-run local scan from carry-in h0, y in-register,
// skip + gate, write y hi/lo bf16 over the uc planes (element read strictly
// before written by its sole owner thread).
// ---------------------------------------------------------------------------
__global__ __launch_bounds__(256) void scan_chunk_final(
    const float* __restrict__ delta, const u16* uch, const u16* ucl,
    const float* __restrict__ xdbl, const float* __restrict__ xz,
    const float* __restrict__ A_log, const float* __restrict__ Dv,
    const float* __restrict__ h0, u16* yh, u16* yl) {
  const int t = blockIdx.x * 256 + threadIdx.x;
  const int d = t & (DI - 1);
  const int b = (t >> 11) & (Bc - 1);
  const int c = t >> 12;
  const int bd = (b << 11) | d;

  float Av2[DS];
  {
    const float4* ap = reinterpret_cast<const float4*>(&A_log[(size_t)d * DS]);
    #pragma unroll
    for (int q = 0; q < 4; ++q) {
      float4 a = ap[q];
      Av2[4*q+0] = -LOG2E * __expf(a.x);
      Av2[4*q+1] = -LOG2E * __expf(a.y);
      Av2[4*q+2] = -LOG2E * __expf(a.z);
      Av2[4*q+3] = -LOG2E * __expf(a.w);
    }
  }
  const float Dd = Dv[d];
  float h[DS];
  {
    const float4* hp = reinterpret_cast<const float4*>(&h0[(size_t)c * BDS + (size_t)bd * DS]);
    #pragma unroll
    for (int q = 0; q < 4; ++q) {
      float4 hv = hp[q];
      h[4*q+0] = hv.x; h[4*q+1] = hv.y; h[4*q+2] = hv.z; h[4*q+3] = hv.w;
    }
  }
  const size_t rowbase = (size_t)(b * Lc + c * CH);
  const float* dp  = delta + rowbase * DI + d;
  const u16*   uhp = uch   + rowbase * DI + d;
  const u16*   ulp = ucl   + rowbase * DI + d;
  const float* zp  = xz    + rowbase * (2 * DI) + DI + d;
  const float4* xp = reinterpret_cast<const float4*>(xdbl + rowbase * NX + DR);
  u16* yhp = yh + rowbase * DI + d;
  u16* ylp = yl + rowbase * DI + d;

  float dt = dp[0];
  float ut = b2f(uhp[0]) + b2f(ulp[0]);
  float zt = zp[0];
  float4 B0 = xp[0], B1 = xp[1], B2 = xp[2], B3 = xp[3];
  float4 C0 = xp[4], C1 = xp[5], C2 = xp[6], C3 = xp[7];

  for (int l = 0; l < CH; ++l) {
    const int ln = (l + 1 < CH) ? l + 1 : l;
    float dtn = dp[ln * DI];
    float utn = b2f(uhp[ln * DI]) + b2f(ulp[ln * DI]);
    float ztn = zp[ln * (2 * DI)];
    const float4* xn = xp + ln * (NX / 4);
    float4 B0n = xn[0], B1n = xn[1], B2n = xn[2], B3n = xn[3];
    float4 C0n = xn[4], C1n = xn[5], C2n = xn[6], C3n = xn[7];

    float Bs[16], Cs[16];
    *reinterpret_cast<float4*>(&Bs[0])  = B0;
    *reinterpret_cast<float4*>(&Bs[4])  = B1;
    *reinterpret_cast<float4*>(&Bs[8])  = B2;
    *reinterpret_cast<float4*>(&Bs[12]) = B3;
    *reinterpret_cast<float4*>(&Cs[0])  = C0;
    *reinterpret_cast<float4*>(&Cs[4])  = C1;
    *reinterpret_cast<float4*>(&Cs[8])  = C2;
    *reinterpret_cast<float4*>(&Cs[12]) = C3;
    const float dtu = dt * ut;
    float y0 = 0.f, y1 = 0.f;
    #pragma unroll
    for (int s = 0; s < DS; ++s) {
      float dA = exp2f(dt * Av2[s]);
      h[s] = fmaf(dA, h[s], dtu * Bs[s]);
      if (s & 1) y1 = fmaf(h[s], Cs[s], y1);
      else       y0 = fmaf(h[s], Cs[s], y0);
    }
    float gate = zt * __frcp_rn(1.f + exp2f(-LOG2E * zt));
    float y = (y0 + y1 + Dd * ut) * gate;
    u16 hh = f2b(y);
    yhp[l * DI] = hh;
    ylp[l * DI] = f2b(y - b2f(hh));

    dt = dtn; ut = utn; zt = ztn;
    B0 = B0n; B1 = B1n; B2 = B2n; B3 = B3n;
    C0 = C0n; C1 = C1n; C2 = C2n; C3 = C3n;
  }
}

// ---------------------------------------------------------------------------
extern "C" void kernel_launch(void* const* d_in, const int* in_sizes, int n_in,
                              void* d_out, int out_size, void* d_ws, size_t ws_size,
                              hipStream_t stream) {
  const float* x        = (const float*)d_in[0];
  const float* W_in     = (const float*)d_in[1];
  const float* conv_w   = (const float*)d_in[2];
  const float* conv_b   = (const float*)d_in[3];
  const float* W_xproj  = (const float*)d_in[4];
  const float* W_dtproj = (const float*)d_in[5];
  const float* dt_bias  = (const float*)d_in[6];
  const float* A_log    = (const float*)d_in[7];
  const float* Dv       = (const float*)d_in[8];
  const float* W_out    = (const float*)d_in[9];
  float* out = (float*)d_out;

  char* W = (char*)d_ws;
  size_t off = 0;
  float* xz  = (float*)(W + off);  off += (size_t)BL * 4096 * 4;    // 64 MB
  size_t delta_off = off;
  u16* xh   = (u16*)(W + off);     off += (size_t)BL * DM * 2;      // 8 MB
  u16* xl   = (u16*)(W + off);     off += (size_t)BL * DM * 2;      // 8 MB
  u16* Wih  = (u16*)(W + off);     off += (size_t)(2 * DI) * DM * 2;// 8 MB
  u16* Wil  = (u16*)(W + off);     off += (size_t)(2 * DI) * DM * 2;// 8 MB
  float* delta = (float*)(W + delta_off);  // 32 MB, aliases xh..Wil (dead post in_proj)
  u16* uch  = (u16*)(W + off);     off += (size_t)BL * DI * 2;      // 16 MB
  u16* ucl  = (u16*)(W + off);     off += (size_t)BL * DI * 2;      // 16 MB
  u16* Wxh  = (u16*)(W + off);     off += (size_t)128 * DI * 2;     // 0.5 MB (padded)
  u16* Wxl  = (u16*)(W + off);     off += (size_t)128 * DI * 2;
  float* xdbl = (float*)(W + off); off += (size_t)BL * NX * 4;      // 1.5 MB
  u16* xdh  = (u16*)(W + off);     off += (size_t)BL * NX * 2;
  u16* xdl  = (u16*)(W + off);     off += (size_t)BL * NX * 2;
  u16* Wdh  = (u16*)(W + off);     off += (size_t)DI * DR * 2;
  u16* Wdl  = (u16*)(W + off);     off += (size_t)DI * DR * 2;
  u16* Woh  = (u16*)(W + off);     off += (size_t)DM * DI * 2;      // 4 MB
  u16* Wol  = (u16*)(W + off);     off += (size_t)DM * DI * 2;      // 4 MB
  float* Pa = (float*)(W + off);   off += (size_t)NC * BDS * 4;     // 8 MB
  float* hA = (float*)(W + off);   off += (size_t)NC * BDS * 4;     // 8 MB
  float* h0 = Pa;                  // pass B writes h0 in-place over Pa
  float* pbuf = Pa;                // x_proj split-K partials (12.6 MB, dead
                                   // before scan_local writes Pa/hA)
  u16* yh = uch;                   // pass C writes y over uc planes (safe)
  u16* yl = ucl;

  // 0) fused conversions to bf16 hi/lo planes (one kernel)
  cvt_all<<<(CVT_TOT + 255) / 256, 256, 0, stream>>>(
      x, W_in, W_xproj, W_dtproj, W_out,
      xh, xl, Wih, Wil, Wxh, Wxl, Wdh, Wdl, Woh, Wol);

  // 1) in_proj: xz = x @ W_in^T   (M=4096, N=4096, K=1024)
  gemm_mfma<0><<<dim3(BL / 128, (2 * DI) / 128, 1), 256, 0, stream>>>(
      xh, xl, Wih, Wil, nullptr, xz, BL, 2 * DI, DM, DM, DM, 2 * DI, 0);

  // 2) depthwise causal conv + SiLU -> uc hi/lo planes (4 elems/thread)
  conv_silu4<<<(BL * DI / 4) / 256, 256, 0, stream>>>(xz, conv_w, conv_b, uch, ucl);

  // 3) x_proj split-K=8: partials pbuf[sk][BL][96] = u_c @ W_xproj^T slices
  gemm_mfma<0><<<dim3(BL / 128, 1, NSK), 256, 0, stream>>>(
      uch, ucl, Wxh, Wxl, nullptr, pbuf, BL, NX, DI / NSK, DI, DI, NX,
      (size_t)BL * NX);

  // 3b) reduce partials -> xdbl fp32 + hi/lo planes (fused cvt)
  xproj_reduce<<<(BL * NX / 4) / 256, 256, 0, stream>>>(pbuf, xdbl, xdh, xdl);

  // 4) dt_proj + softplus: delta = softplus(xdbl[:, :64] @ W_dtproj^T + bias)
  gemm_mfma<1><<<dim3(BL / 128, DI / 128, 1), 256, 0, stream>>>(
      xdh, xdl, Wdh, Wdl, dt_bias, delta, BL, DI, DR, NX, DR, DI, 0);

  // 5) chunked selective scan (3 passes, d-parallel A/C)
  scan_chunk_local<<<(Bc * DI * NC) / 256, 256, 0, stream>>>(
      delta, uch, ucl, xdbl, A_log, Pa, hA);
  scan_chunk_carry<<<BDS / 256, 256, 0, stream>>>(Pa, hA);
  scan_chunk_final<<<(Bc * DI * NC) / 256, 256, 0, stream>>>(
      delta, uch, ucl, xdbl, xz, A_log, Dv, h0, yh, yl);

  // 6) out_proj: out = y @ W_out^T  (M=4096, N=1024, K=2048)
  gemm_mfma<0><<<dim3(BL / 128, DM / 128, 1), 256, 0, stream>>>(
      yh, yl, Woh, Wol, nullptr, out, BL, DM, DI, DI, DI, DM, 0);
}